// Round 1
// baseline (221.641 us; speedup 1.0000x reference)
//
#include <hip/hip_runtime.h>

// Problem constants
#define MATN   2048
#define NTRIU  2098176           // 2048*2049/2
#define NBATCH 32

// Per-batch float4 count = N*N/4 = 2^20 ; per-row float4 count = N/4 = 2^9.
// Flat triu index for (r,c), r<=c:  rowoff(r) + (c - r), rowoff(r) = r*N - r*(r-1)/2.

__global__ __launch_bounds__(256)
void triu_scatter_kernel(const float* __restrict__ in, float* __restrict__ out, int total4) {
    float4* __restrict__ out4 = reinterpret_cast<float4*>(out);
    const int stride = gridDim.x * blockDim.x;
    for (int idx = blockIdx.x * blockDim.x + threadIdx.x; idx < total4; idx += stride) {
        const int b   = idx >> 20;            // / (N*N/4)
        const int rem = idx & ((1 << 20) - 1);
        const int r   = rem >> 9;             // / (N/4)
        const int c0  = (rem & 511) << 2;     // column of first element in the float4

        // input flat index for column c in this row: g + c
        // g = b*NTRIU + r*N - r*(r-1)/2 - r
        const int g = b * NTRIU + r * MATN - ((r * (r - 1)) >> 1) - r;

        float4 v;
        if (c0 >= r) {
            // fully inside the upper triangle: 4 consecutive input elements
            const float* __restrict__ p = in + g + c0;
            v.x = p[0]; v.y = p[1]; v.z = p[2]; v.w = p[3];
        } else if (c0 + 3 < r) {
            // fully below the diagonal: zeros
            v = make_float4(0.f, 0.f, 0.f, 0.f);
        } else {
            // straddles the diagonal (at most one thread per row)
            v.x = (c0 + 0 >= r) ? in[g + c0 + 0] : 0.f;
            v.y = (c0 + 1 >= r) ? in[g + c0 + 1] : 0.f;
            v.z = (c0 + 2 >= r) ? in[g + c0 + 2] : 0.f;
            v.w = (c0 + 3 >= r) ? in[g + c0 + 3] : 0.f;
        }
        out4[idx] = v;
    }
}

extern "C" void kernel_launch(void* const* d_in, const int* in_sizes, int n_in,
                              void* d_out, int out_size, void* d_ws, size_t ws_size,
                              hipStream_t stream) {
    const float* in = (const float*)d_in[0];
    float* out = (float*)d_out;

    const int total4 = (NBATCH * MATN * MATN) / 4;  // 33,554,432
    const int block = 256;
    const int grid = 4096;                          // grid-stride; 16 CUs-worth of blocks per CU
    triu_scatter_kernel<<<grid, block, 0, stream>>>(in, out, total4);
}

// Round 2
// 158.972 us; speedup vs baseline: 1.3942x; 1.3942x over previous
//
#include <hip/hip_runtime.h>

// Problem constants
#define MATN   2048
#define NTRIU  2098176           // 2048*2049/2
#define NBATCH 32

// Tiles: one wave (64 lanes) handles a 256-column segment of one row.
// 8 tiles per row, 2048 rows, 32 batches -> 524288 tiles.
#define NTILES (NBATCH * MATN * 8)

// Flat triu index for (r,c), r<=c:  g + c, where g = b*NTRIU + r*N - r*(r-1)/2 - r.
// Lane l covers columns seg + 64k + l (k=0..3): every load and store
// instruction is a contiguous 256B wave access (no inter-lane stride).

__global__ __launch_bounds__(256)
void triu_scatter_kernel(const float* __restrict__ in, float* __restrict__ out) {
    const int lane   = threadIdx.x & 63;
    const int warp   = (blockIdx.x * blockDim.x + threadIdx.x) >> 6;
    const int nwarps = (gridDim.x * blockDim.x) >> 6;

    for (int tile = warp; tile < NTILES; tile += nwarps) {
        const int b   = tile >> 14;           // / (2048*8)
        const int rem = tile & 16383;
        const int r   = rem >> 3;             // row
        const int seg = (rem & 7) << 8;       // starting column of 256-wide segment

        const int g = b * NTRIU + r * MATN - ((r * (r - 1)) >> 1) - r;
        const int out_base = ((b << 11) + r) << 11;   // (b*2048 + r)*2048, fits int

        #pragma unroll
        for (int k = 0; k < 4; ++k) {
            const int c = seg + (k << 6) + lane;
            float v = 0.f;
            if (c >= r) v = in[g + c];        // wave-uniform except the diagonal tile
            __builtin_nontemporal_store(v, &out[out_base + c]);
        }
    }
}

extern "C" void kernel_launch(void* const* d_in, const int* in_sizes, int n_in,
                              void* d_out, int out_size, void* d_ws, size_t ws_size,
                              hipStream_t stream) {
    const float* in = (const float*)d_in[0];
    float* out = (float*)d_out;

    const int block = 256;
    const int grid  = 4096;   // 16384 waves -> 32 tiles/wave, grid-stride
    triu_scatter_kernel<<<grid, block, 0, stream>>>(in, out);
}

// Round 4
// 152.273 us; speedup vs baseline: 1.4555x; 1.0440x over previous
//
#include <hip/hip_runtime.h>

// Problem constants
#define MATN   2048
#define NTRIU  2098176           // 2048*2049/2
#define NBATCH 32

// Tiles: one wave (64 lanes) handles a 256-column segment of one row.
// 8 tiles per row, 2048 rows, 32 batches -> 524288 tiles.
#define NTILES (NBATCH * MATN * 8)

// clang-native float4 (works with __builtin_nontemporal_store, unlike
// HIP_vector_type<float,4>)
typedef float f32x4 __attribute__((ext_vector_type(4)));

// Reads: lane-contiguous scalar loads (row base g is only 4B-aligned).
// Stores: aligned dwordx4 nontemporal (16B/lane = 1KiB/wave-instruction).
// Bridge: wave-private LDS repack; same-wave DS ops are ordered, no barrier.

__global__ __launch_bounds__(256)
void triu_scatter_kernel(const float* __restrict__ in, float* __restrict__ out) {
    __shared__ float lbuf[4][256];            // 1 KiB per wave, 4 waves/block
    const int lane   = threadIdx.x & 63;
    const int wid    = threadIdx.x >> 6;
    const int warp   = (blockIdx.x * blockDim.x + threadIdx.x) >> 6;
    const int nwarps = (gridDim.x * blockDim.x) >> 6;
    float* __restrict__ lw = lbuf[wid];

    for (int tile = warp; tile < NTILES; tile += nwarps) {
        const int b   = tile >> 14;           // / (2048*8)
        const int rem = tile & 16383;
        const int r   = rem >> 3;             // row
        const int seg = (rem & 7) << 8;       // starting column of 256-wide segment

        const int g = b * NTRIU + r * MATN - ((r * (r - 1)) >> 1) - r;
        const int out_base = ((b << 11) + r) << 11;   // (b*2048 + r)*2048

        // 1) contiguous scalar gather: lane l covers columns seg + 64k + l
        float v[4];
        #pragma unroll
        for (int k = 0; k < 4; ++k) {
            const int c = seg + (k << 6) + lane;
            v[k] = (c >= r) ? in[g + c] : 0.f;
        }
        // 2) wave-synchronous LDS repack (write lane-contiguous, read b128)
        #pragma unroll
        for (int k = 0; k < 4; ++k)
            lw[(k << 6) + lane] = v[k];
        const f32x4 o = *reinterpret_cast<const f32x4*>(&lw[lane << 2]);
        // 3) aligned 16B/lane nontemporal store
        __builtin_nontemporal_store(
            o, reinterpret_cast<f32x4*>(&out[out_base + seg + (lane << 2)]));
    }
}

extern "C" void kernel_launch(void* const* d_in, const int* in_sizes, int n_in,
                              void* d_out, int out_size, void* d_ws, size_t ws_size,
                              hipStream_t stream) {
    const float* in = (const float*)d_in[0];
    float* out = (float*)d_out;

    const int block = 256;
    const int grid  = 4096;   // 16384 waves -> 32 tiles/wave, grid-stride
    triu_scatter_kernel<<<grid, block, 0, stream>>>(in, out);
}